// Round 4
// baseline (5334.114 us; speedup 1.0000x reference)
//
#include <hip/hip_runtime.h>
#include <hip/hip_bf16.h>

#define NN 100000
#define NE 3200000
#define NG 1000
#define BN_EPS 1e-5f

#define BKT_SH 6            // 64 nodes per bucket
#define BKTN 64
#define NBKT 1563           // ceil(NN/64)
#define CHUNK 8192          // edges per bin_kernel block
#define NBINBLK 391         // ceil(NE/CHUNK)

__device__ __forceinline__ unsigned short f2bf(float f) {
    unsigned int u = __builtin_bit_cast(unsigned int, f);
    u += 0x7FFFu + ((u >> 16) & 1u);        // round-to-nearest-even
    return (unsigned short)(u >> 16);
}
__device__ __forceinline__ float bf2f(unsigned int h16) {
    return __builtin_bit_cast(float, h16 << 16);
}

// ---------------- bucket histogram ----------------
__global__ __launch_bounds__(256) void bucket_count_kernel(const int* __restrict__ dst,
                                                           int* __restrict__ bcnt) {
    __shared__ int h[NBKT];
    int t = threadIdx.x;
    for (int i = t; i < NBKT; i += 256) h[i] = 0;
    __syncthreads();
    int gid = blockIdx.x * 256 + t;
    for (int e = gid; e < NE; e += NBINBLK * 256) atomicAdd(&h[dst[e] >> BKT_SH], 1);
    __syncthreads();
    for (int i = t; i < NBKT; i += 256) if (h[i]) atomicAdd(&bcnt[i], h[i]);
}

// ---------------- exclusive scan of bucket counts ----------------
__global__ void bucket_scan_kernel(const int* __restrict__ bcnt, int* __restrict__ bbase,
                                   int* __restrict__ bcur) {
    __shared__ int wsum[16];
    __shared__ int lcarry;
    int t = threadIdx.x, lane = t & 63, w = t >> 6;
    if (t == 0) lcarry = 0;
    __syncthreads();
    for (int base = 0; base < NBKT; base += 1024) {
        int i = base + t;
        int v = (i < NBKT) ? bcnt[i] : 0;
        int incl = v;
        #pragma unroll
        for (int d = 1; d < 64; d <<= 1) { int u = __shfl_up(incl, d, 64); if (lane >= d) incl += u; }
        if (lane == 63) wsum[w] = incl;
        __syncthreads();
        if (w == 0) {
            int s = (lane < 16) ? wsum[lane] : 0;
            #pragma unroll
            for (int d = 1; d < 16; d <<= 1) { int u = __shfl_up(s, d, 64); if (lane >= d) s += u; }
            if (lane < 16) wsum[lane] = s;
        }
        __syncthreads();
        int excl = lcarry + (w ? wsum[w - 1] : 0) + incl - v;
        if (i < NBKT) { bbase[i] = excl; bcur[i] = excl; }
        __syncthreads();
        if (t == 0) lcarry += wsum[15];
        __syncthreads();
    }
}

// ---------------- binning: group edges by 64-node bucket ----------------
__global__ __launch_bounds__(256) void bin_kernel(const int* __restrict__ src,
        const int* __restrict__ dst, int* __restrict__ bcur,
        unsigned int* __restrict__ ebin) {
    __shared__ unsigned int ebuf[CHUNK];        // 32 KB
    __shared__ unsigned short bids[CHUNK];      // 16 KB
    __shared__ int hist[NBKT], lbase[NBKT], lcur[NBKT], delta[NBKT];   // 25 KB
    __shared__ int wsum4[4];
    __shared__ int carry;
    int t = threadIdx.x;
    int lane = t & 63, w = t >> 6;
    int c0 = blockIdx.x * CHUNK;
    int cnt = min(CHUNK, NE - c0);
    for (int i = t; i < NBKT; i += 256) hist[i] = 0;
    if (t == 0) carry = 0;
    __syncthreads();
    for (int i = t; i < cnt; i += 256) atomicAdd(&hist[dst[c0 + i] >> BKT_SH], 1);
    __syncthreads();
    for (int bb = 0; bb < NBKT; bb += 256) {
        int i = bb + t;
        int v = (i < NBKT) ? hist[i] : 0;
        int incl = v;
        #pragma unroll
        for (int d2 = 1; d2 < 64; d2 <<= 1) { int u = __shfl_up(incl, d2, 64); if (lane >= d2) incl += u; }
        if (lane == 63) wsum4[w] = incl;
        __syncthreads();
        int wo = 0;
        if (w > 0) wo = wsum4[0];
        if (w > 1) wo += wsum4[1];
        if (w > 2) wo += wsum4[2];
        int excl = carry + wo + incl - v;
        if (i < NBKT) { lbase[i] = excl; lcur[i] = excl; }
        int tot = wsum4[0] + wsum4[1] + wsum4[2] + wsum4[3];
        __syncthreads();
        if (t == 0) carry += tot;
        __syncthreads();
    }
    for (int b = t; b < NBKT; b += 256) {
        int hh = hist[b];
        delta[b] = (hh ? atomicAdd(&bcur[b], hh) : 0) - lbase[b];
    }
    __syncthreads();
    for (int i = t; i < cnt; i += 256) {
        int d = dst[c0 + i];
        int s = src[c0 + i];
        int b = d >> BKT_SH;
        unsigned int entry = ((unsigned int)s << BKT_SH) | (unsigned int)(d & (BKTN - 1));
        int p = atomicAdd(&lcur[b], 1);
        ebuf[p] = entry;
        bids[p] = (unsigned short)b;
    }
    __syncthreads();
    for (int i = t; i < cnt; i += 256) {
        ebin[delta[bids[i]] + i] = ebuf[i];
    }
}

// ---------------- pack x f32 -> u32 (bf16 pair: channels l, l+64) ----------------
__global__ void pack_x_kernel(const float* __restrict__ x, unsigned int* __restrict__ xp) {
    int tid = blockIdx.x * 256 + threadIdx.x;   // NN*64 exact
    int n = tid >> 6, l = tid & 63;
    float a = x[(size_t)n * 128 + l];
    float c = x[(size_t)n * 128 + l + 64];
    xp[tid] = (unsigned int)f2bf(a) | ((unsigned int)f2bf(c) << 16);
}

// ---------------- aggregation: LDS f32 accumulators + ds_add atomics ----------------
// out[i] = x[i] + sum_{j->i} x[j]; PACKED=1: rows are u32(bf16lo=c, bf16hi=c+64) at
// stride srow u32; PACKED=0: f32 rows stride 128.
template<int PACKED>
__global__ __launch_bounds__(256) void aggregate2_kernel(const void* __restrict__ xin,
        int srow, const int* __restrict__ bbase, const int* __restrict__ bcnt,
        const unsigned int* __restrict__ ebin, float* __restrict__ out) {
    __shared__ float acc[BKTN][128];            // 32 KB
    int t = threadIdx.x, lane = t & 63, w = t >> 6;
    int b = blockIdx.x;
    int node0 = b << BKT_SH;
    if (PACKED) {
        const unsigned int* xp = (const unsigned int*)xin;
        for (int i = t; i < BKTN * 64; i += 256) {
            int r = i >> 6, l = i & 63;
            int node = node0 + r;
            unsigned int u = (node < NN) ? xp[(size_t)node * srow + l] : 0u;
            acc[r][l] = bf2f(u & 0xFFFFu);
            acc[r][l + 64] = bf2f(u >> 16);
        }
    } else {
        const float* xf = (const float*)xin;
        for (int i = t; i < BKTN * 128; i += 256) {
            int r = i >> 7, c = i & 127;
            int node = node0 + r;
            acc[r][c] = (node < NN) ? xf[(size_t)node * 128 + c] : 0.f;
        }
    }
    __syncthreads();
    int base = bbase[b], cnt = bcnt[b];
    int start = base + (cnt * w) / 4;
    int end = base + (cnt * (w + 1)) / 4;
    const unsigned int* xp = (const unsigned int*)xin;
    const float* xf = (const float*)xin;
    int p = start;
    for (; p + 64 <= end; p += 64) {
        unsigned int ev = ebin[p + lane];
        #pragma unroll 8
        for (int j = 0; j < 64; ++j) {
            unsigned int e = __shfl(ev, j, 64);
            int sv = e >> BKT_SH;
            int ni = e & (BKTN - 1);
            float lo, hi;
            if (PACKED) {
                unsigned int u = xp[(size_t)sv * srow + lane];
                lo = bf2f(u & 0xFFFFu); hi = bf2f(u >> 16);
            } else {
                lo = xf[(size_t)sv * 128 + lane];
                hi = xf[(size_t)sv * 128 + lane + 64];
            }
            unsafeAtomicAdd(&acc[ni][lane], lo);
            unsafeAtomicAdd(&acc[ni][lane + 64], hi);
        }
    }
    if (p < end) {
        int n = end - p;
        unsigned int ev = (lane < n) ? ebin[p + lane] : 0u;
        for (int j = 0; j < n; ++j) {
            unsigned int e = __shfl(ev, j, 64);
            int sv = e >> BKT_SH;
            int ni = e & (BKTN - 1);
            float lo, hi;
            if (PACKED) {
                unsigned int u = xp[(size_t)sv * srow + lane];
                lo = bf2f(u & 0xFFFFu); hi = bf2f(u >> 16);
            } else {
                lo = xf[(size_t)sv * 128 + lane];
                hi = xf[(size_t)sv * 128 + lane + 64];
            }
            unsafeAtomicAdd(&acc[ni][lane], lo);
            unsafeAtomicAdd(&acc[ni][lane + 64], hi);
        }
    }
    __syncthreads();
    float4* o4 = (float4*)out;
    for (int i = t; i < BKTN * 32; i += 256) {
        int r = i >> 5, c4 = i & 31;
        int node = node0 + r;
        if (node < NN) o4[(size_t)node * 32 + c4] = *(float4*)&acc[r][c4 * 4];
    }
}

// ---------------- f32 GEMM: C = [relu](A[M,128] @ W[128,128] + b) ----------------
template<int RELU>
__global__ __launch_bounds__(256, 2) void gemm128_kernel(const float* __restrict__ A,
        const float* __restrict__ W, const float* __restrict__ bias,
        float* __restrict__ Cout, int M) {
    __shared__ float As[64][132];
    __shared__ float Ws[128][64];
    int t = threadIdx.x;
    int bm = blockIdx.x, bn = blockIdx.y;
    int row0 = bm * 64;
    {
        const float4* A4 = (const float4*)A;
        #pragma unroll
        for (int i = 0; i < 8; ++i) {
            int idx = i * 256 + t;
            int r = idx >> 5, c4 = idx & 31;
            int gr = row0 + r;
            float4 v = (gr < M) ? A4[(size_t)gr * 32 + c4] : make_float4(0.f, 0.f, 0.f, 0.f);
            *(float4*)&As[r][c4 * 4] = v;
        }
        const float4* W4 = (const float4*)W;
        #pragma unroll
        for (int i = 0; i < 8; ++i) {
            int idx = i * 256 + t;
            int k = idx >> 4, c4 = idx & 15;
            float4 v = W4[(size_t)k * 32 + bn * 16 + c4];
            *(float4*)&Ws[k][c4 * 4] = v;
        }
    }
    __syncthreads();
    int tc = t & 15, tr = t >> 4;
    int c0 = tc * 4;
    float acc[4][4] = {};
    for (int k = 0; k < 128; k += 4) {
        float4 a[4], w[4];
        #pragma unroll
        for (int j = 0; j < 4; ++j) a[j] = *(const float4*)&As[tr * 4 + j][k];
        #pragma unroll
        for (int kk = 0; kk < 4; ++kk) w[kk] = *(const float4*)&Ws[k + kk][c0];
        #pragma unroll
        for (int j = 0; j < 4; ++j) {
            float av[4] = {a[j].x, a[j].y, a[j].z, a[j].w};
            #pragma unroll
            for (int kk = 0; kk < 4; ++kk) {
                acc[j][0] += av[kk] * w[kk].x;
                acc[j][1] += av[kk] * w[kk].y;
                acc[j][2] += av[kk] * w[kk].z;
                acc[j][3] += av[kk] * w[kk].w;
            }
        }
    }
    float4 b4 = *(const float4*)&bias[bn * 64 + c0];
    #pragma unroll
    for (int j = 0; j < 4; ++j) {
        int gr = row0 + tr * 4 + j;
        if (gr < M) {
            float4 v = make_float4(acc[j][0] + b4.x, acc[j][1] + b4.y,
                                   acc[j][2] + b4.z, acc[j][3] + b4.w);
            if (RELU) {
                v.x = fmaxf(v.x, 0.f); v.y = fmaxf(v.y, 0.f);
                v.z = fmaxf(v.z, 0.f); v.w = fmaxf(v.w, 0.f);
            }
            *(float4*)&Cout[(size_t)gr * 128 + bn * 64 + c0] = v;
        }
    }
}

// ---------------- BN stats: per-channel sum & sumsq ----------------
__global__ void bn_stats_kernel(const float* __restrict__ U, float* __restrict__ stats) {
    int tid = blockIdx.x * 256 + threadIdx.x;
    int chn = tid & 127;
    float s = 0.f, sq = 0.f;
    const int total = NN * 128;
    for (int i = tid; i < total; i += 2048 * 256) {
        float v = U[i];
        s += v; sq += v * v;
    }
    atomicAdd(&stats[chn], s);
    atomicAdd(&stats[128 + chn], sq);
}

// ---------------- BN + ReLU + in-place bf16 pack (row prefix, stride 128 u32) ----------------
__global__ void bn_relu_pack_kernel(float* __restrict__ F, const float* __restrict__ stats,
        const float* __restrict__ gamma, const float* __restrict__ beta) {
    int tid = blockIdx.x * 256 + threadIdx.x;   // NN*64 exact, wave == one node
    int n = tid >> 6, l = tid & 63;
    const float inv = 1.0f / NN;
    float u0 = F[(size_t)n * 128 + l];
    float u1 = F[(size_t)n * 128 + l + 64];
    float m0 = stats[l] * inv;
    float v0 = stats[128 + l] * inv - m0 * m0;
    float m1 = stats[l + 64] * inv;
    float v1 = stats[192 + l] * inv - m1 * m1;
    float o0 = fmaxf((u0 - m0) * rsqrtf(v0 + BN_EPS) * gamma[l] + beta[l], 0.f);
    float o1 = fmaxf((u1 - m1) * rsqrtf(v1 + BN_EPS) * gamma[l + 64] + beta[l + 64], 0.f);
    ((unsigned int*)F)[(size_t)n * 128 + l] =
        (unsigned int)f2bf(o0) | ((unsigned int)f2bf(o1) << 16);
}

// ---------------- pooling over packed rows ----------------
__global__ void pool_kernel(const unsigned int* __restrict__ hb, int srow,
                            const int* __restrict__ batch, float* __restrict__ pooled) {
    int g = blockIdx.x;
    int l = threadIdx.x;   // 64
    int a = 0, b = NN;
    while (a < b) { int m = (a + b) >> 1; if (batch[m] < g) a = m + 1; else b = m; }
    int start = a;
    b = NN;
    while (a < b) { int m = (a + b) >> 1; if (batch[m] < g + 1) a = m + 1; else b = m; }
    int end = a;
    float s0 = 0.f, s1 = 0.f;
    for (int i = start; i < end; ++i) {
        unsigned int u = hb[(size_t)i * srow + l];
        s0 += bf2f(u & 0xFFFFu);
        s1 += bf2f(u >> 16);
    }
    pooled[g * 128 + l] = s0;
    pooled[g * 128 + l + 64] = s1;
}

// ---------------- head: logits + log_softmax ----------------
__global__ void head_kernel(const float* __restrict__ pooled, const float* __restrict__ Wlin,
                            const float* __restrict__ blin, float* __restrict__ out) {
    int g = blockIdx.x;
    int lane = threadIdx.x;  // 64
    float2 p = ((const float2*)pooled)[g * 64 + lane];
    float l[10];
    #pragma unroll
    for (int o = 0; o < 10; ++o) {
        float partial = p.x * Wlin[(2 * lane) * 10 + o] + p.y * Wlin[(2 * lane + 1) * 10 + o];
        #pragma unroll
        for (int m = 1; m < 64; m <<= 1) partial += __shfl_xor(partial, m, 64);
        l[o] = partial + blin[o];
    }
    float mx = l[0];
    #pragma unroll
    for (int o = 1; o < 10; ++o) mx = fmaxf(mx, l[o]);
    float se = 0.f;
    #pragma unroll
    for (int o = 0; o < 10; ++o) se += expf(l[o] - mx);
    float lse = mx + logf(se);
    if (lane == 0) {
        #pragma unroll
        for (int o = 0; o < 10; ++o) out[g * 10 + o] = l[o] - lse;
    }
}

extern "C" void kernel_launch(void* const* d_in, const int* in_sizes, int n_in,
                              void* d_out, int out_size, void* d_ws, size_t ws_size,
                              hipStream_t stream) {
    const float* x    = (const float*)d_in[0];
    const int*   edge = (const int*)d_in[1];   // [2][NE]
    const int*   batch= (const int*)d_in[2];
    const float* W1a  = (const float*)d_in[3];
    const float* b1a  = (const float*)d_in[4];
    const float* W1b  = (const float*)d_in[5];
    const float* b1b  = (const float*)d_in[6];
    const float* g1   = (const float*)d_in[7];
    const float* be1  = (const float*)d_in[8];
    const float* W2a  = (const float*)d_in[9];
    const float* b2a  = (const float*)d_in[10];
    const float* W2b  = (const float*)d_in[11];
    const float* b2b  = (const float*)d_in[12];
    const float* g2   = (const float*)d_in[13];
    const float* be2  = (const float*)d_in[14];
    const float* Wlin = (const float*)d_in[15];
    const float* blin = (const float*)d_in[16];
    float* out = (float*)d_out;

    char* ws = (char*)d_ws;
    size_t off = 0;
    auto alloc = [&](size_t bytes) -> void* {
        void* p = ws + off; off += (bytes + 255) & ~(size_t)255; return p;
    };
    float* F1     = (float*)alloc((size_t)NN * 128 * 4);
    float* F2     = (float*)alloc((size_t)NN * 128 * 4);
    unsigned int* ebin = (unsigned int*)alloc((size_t)NE * 4);
    int*   bcnt   = (int*)alloc(NBKT * 4);
    int*   bbase  = (int*)alloc(NBKT * 4);
    int*   bcur   = (int*)alloc(NBKT * 4);
    float* stats1 = (float*)alloc(256 * 4);
    float* stats2 = (float*)alloc(256 * 4);
    float* pooled = (float*)alloc(NG * 128 * 4);
    size_t base_need = off;
    bool havePx = (ws_size >= base_need + (size_t)NN * 64 * 4 + 256);
    unsigned int* Px = havePx ? (unsigned int*)alloc((size_t)NN * 64 * 4) : nullptr;

    const int* srcI = edge;
    const int* dstI = edge + NE;

    hipMemsetAsync(bcnt, 0, NBKT * 4, stream);
    hipMemsetAsync(stats1, 0, 256 * 4, stream);
    hipMemsetAsync(stats2, 0, 256 * 4, stream);

    bucket_count_kernel<<<NBINBLK, 256, 0, stream>>>(dstI, bcnt);
    bucket_scan_kernel<<<1, 1024, 0, stream>>>(bcnt, bbase, bcur);
    bin_kernel<<<NBINBLK, 256, 0, stream>>>(srcI, dstI, bcur, ebin);

    dim3 ggrid(1563, 2);
    // ---- layer 1 ----
    if (havePx) {
        pack_x_kernel<<<25000, 256, 0, stream>>>(x, Px);
        aggregate2_kernel<1><<<NBKT, 256, 0, stream>>>(Px, 64, bbase, bcnt, ebin, F1);
    } else {
        aggregate2_kernel<0><<<NBKT, 256, 0, stream>>>(x, 128, bbase, bcnt, ebin, F1);
    }
    gemm128_kernel<1><<<ggrid, 256, 0, stream>>>(F1, W1a, b1a, F2, NN);
    gemm128_kernel<0><<<ggrid, 256, 0, stream>>>(F2, W1b, b1b, F1, NN);
    bn_stats_kernel<<<2048, 256, 0, stream>>>(F1, stats1);
    bn_relu_pack_kernel<<<25000, 256, 0, stream>>>(F1, stats1, g1, be1);
    // ---- layer 2 ----
    aggregate2_kernel<1><<<NBKT, 256, 0, stream>>>(F1, 128, bbase, bcnt, ebin, F2);
    gemm128_kernel<1><<<ggrid, 256, 0, stream>>>(F2, W2a, b2a, F1, NN);
    gemm128_kernel<0><<<ggrid, 256, 0, stream>>>(F1, W2b, b2b, F2, NN);
    bn_stats_kernel<<<2048, 256, 0, stream>>>(F2, stats2);
    bn_relu_pack_kernel<<<25000, 256, 0, stream>>>(F2, stats2, g2, be2);

    pool_kernel<<<NG, 64, 0, stream>>>((const unsigned int*)F2, 128, batch, pooled);
    head_kernel<<<NG, 64, 0, stream>>>(pooled, Wlin, blin, out);
}

// Round 5
// 840.405 us; speedup vs baseline: 6.3471x; 6.3471x over previous
//
#include <hip/hip_runtime.h>
#include <hip/hip_bf16.h>

#define NN 100000
#define NE 3200000
#define NG 1000
#define BN_EPS 1e-5f

#define BKT_SH 6            // 64 nodes per bucket
#define BKTN 64
#define NBKT 1563           // ceil(NN/64)
#define CHUNK 8192          // edges per bin_kernel block
#define NBINBLK 391         // ceil(NE/CHUNK)

__device__ __forceinline__ unsigned short f2bf(float f) {
    unsigned int u = __builtin_bit_cast(unsigned int, f);
    u += 0x7FFFu + ((u >> 16) & 1u);        // round-to-nearest-even
    return (unsigned short)(u >> 16);
}
__device__ __forceinline__ float bf2f(unsigned int h16) {
    return __builtin_bit_cast(float, h16 << 16);
}

// ---------------- bucket histogram ----------------
__global__ __launch_bounds__(256) void bucket_count_kernel(const int* __restrict__ dst,
                                                           int* __restrict__ bcnt) {
    __shared__ int h[NBKT];
    int t = threadIdx.x;
    for (int i = t; i < NBKT; i += 256) h[i] = 0;
    __syncthreads();
    int gid = blockIdx.x * 256 + t;
    for (int e = gid; e < NE; e += NBINBLK * 256) atomicAdd(&h[dst[e] >> BKT_SH], 1);
    __syncthreads();
    for (int i = t; i < NBKT; i += 256) if (h[i]) atomicAdd(&bcnt[i], h[i]);
}

// ---------------- exclusive scan of bucket counts ----------------
__global__ void bucket_scan_kernel(const int* __restrict__ bcnt, int* __restrict__ bbase,
                                   int* __restrict__ bcur) {
    __shared__ int wsum[16];
    __shared__ int lcarry;
    int t = threadIdx.x, lane = t & 63, w = t >> 6;
    if (t == 0) lcarry = 0;
    __syncthreads();
    for (int base = 0; base < NBKT; base += 1024) {
        int i = base + t;
        int v = (i < NBKT) ? bcnt[i] : 0;
        int incl = v;
        #pragma unroll
        for (int d = 1; d < 64; d <<= 1) { int u = __shfl_up(incl, d, 64); if (lane >= d) incl += u; }
        if (lane == 63) wsum[w] = incl;
        __syncthreads();
        if (w == 0) {
            int s = (lane < 16) ? wsum[lane] : 0;
            #pragma unroll
            for (int d = 1; d < 16; d <<= 1) { int u = __shfl_up(s, d, 64); if (lane >= d) s += u; }
            if (lane < 16) wsum[lane] = s;
        }
        __syncthreads();
        int excl = lcarry + (w ? wsum[w - 1] : 0) + incl - v;
        if (i < NBKT) { bbase[i] = excl; bcur[i] = excl; }
        __syncthreads();
        if (t == 0) lcarry += wsum[15];
        __syncthreads();
    }
}

// ---------------- binning: group edges by 64-node bucket ----------------
__global__ __launch_bounds__(256) void bin_kernel(const int* __restrict__ src,
        const int* __restrict__ dst, int* __restrict__ bcur,
        unsigned int* __restrict__ ebin) {
    __shared__ unsigned int ebuf[CHUNK];        // 32 KB
    __shared__ unsigned short bids[CHUNK];      // 16 KB
    __shared__ int hist[NBKT], lbase[NBKT], lcur[NBKT], delta[NBKT];   // 25 KB
    __shared__ int wsum4[4];
    __shared__ int carry;
    int t = threadIdx.x;
    int lane = t & 63, w = t >> 6;
    int c0 = blockIdx.x * CHUNK;
    int cnt = min(CHUNK, NE - c0);
    for (int i = t; i < NBKT; i += 256) hist[i] = 0;
    if (t == 0) carry = 0;
    __syncthreads();
    for (int i = t; i < cnt; i += 256) atomicAdd(&hist[dst[c0 + i] >> BKT_SH], 1);
    __syncthreads();
    for (int bb = 0; bb < NBKT; bb += 256) {
        int i = bb + t;
        int v = (i < NBKT) ? hist[i] : 0;
        int incl = v;
        #pragma unroll
        for (int d2 = 1; d2 < 64; d2 <<= 1) { int u = __shfl_up(incl, d2, 64); if (lane >= d2) incl += u; }
        if (lane == 63) wsum4[w] = incl;
        __syncthreads();
        int wo = 0;
        if (w > 0) wo = wsum4[0];
        if (w > 1) wo += wsum4[1];
        if (w > 2) wo += wsum4[2];
        int excl = carry + wo + incl - v;
        if (i < NBKT) { lbase[i] = excl; lcur[i] = excl; }
        int tot = wsum4[0] + wsum4[1] + wsum4[2] + wsum4[3];
        __syncthreads();
        if (t == 0) carry += tot;
        __syncthreads();
    }
    for (int b = t; b < NBKT; b += 256) {
        int hh = hist[b];
        delta[b] = (hh ? atomicAdd(&bcur[b], hh) : 0) - lbase[b];
    }
    __syncthreads();
    for (int i = t; i < cnt; i += 256) {
        int d = dst[c0 + i];
        int s = src[c0 + i];
        int b = d >> BKT_SH;
        unsigned int entry = ((unsigned int)s << BKT_SH) | (unsigned int)(d & (BKTN - 1));
        int p = atomicAdd(&lcur[b], 1);
        ebuf[p] = entry;
        bids[p] = (unsigned short)b;
    }
    __syncthreads();
    for (int i = t; i < cnt; i += 256) {
        ebin[delta[bids[i]] + i] = ebuf[i];
    }
}

// ---------------- per-bucket counting sort -> per-node CSR ----------------
__global__ __launch_bounds__(256) void sort_kernel(const unsigned int* __restrict__ ebin,
        const int* __restrict__ bbase, const int* __restrict__ bcnt,
        int* __restrict__ noffs, int* __restrict__ csrc) {
    __shared__ int nh[BKTN], ncur[BKTN];
    int b = blockIdx.x, t = threadIdx.x;
    int base = bbase[b], cnt = bcnt[b];
    if (t < BKTN) nh[t] = 0;
    __syncthreads();
    for (int i = t; i < cnt; i += 256) atomicAdd(&nh[ebin[base + i] & (BKTN - 1)], 1);
    __syncthreads();
    if (t < 64) {
        int v = nh[t], incl = v;
        #pragma unroll
        for (int d = 1; d < 64; d <<= 1) { int u = __shfl_up(incl, d, 64); if (t >= d) incl += u; }
        int excl = incl - v;
        ncur[t] = excl;
        int node = (b << BKT_SH) + t;
        if (node < NN) noffs[node] = base + excl;
    }
    if (b == 0 && t == 0) noffs[NN] = NE;
    __syncthreads();
    for (int i = t; i < cnt; i += 256) {
        unsigned int e = ebin[base + i];
        int p = atomicAdd(&ncur[e & (BKTN - 1)], 1);
        csrc[base + p] = (int)(e >> BKT_SH);
    }
}

// ---------------- pack x f32 -> u32 (bf16 pair: channels l, l+64) ----------------
__global__ void pack_x_kernel(const float* __restrict__ x, unsigned int* __restrict__ xp) {
    int tid = blockIdx.x * 256 + threadIdx.x;   // NN*64 exact
    int n = tid >> 6, l = tid & 63;
    float a = x[(size_t)n * 128 + l];
    float c = x[(size_t)n * 128 + l + 64];
    xp[tid] = (unsigned int)f2bf(a) | ((unsigned int)f2bf(c) << 16);
}

// ---------------- aggregation: one wave per node, ILP-8 register accumulate ----------------
// PACKED=1: rows u32(bf16 c | bf16 c+64), stride srow u32. PACKED=0: f32 rows, stride 128.
template<int PACKED>
__global__ __launch_bounds__(256) void aggregate_gather_kernel(const void* __restrict__ xin,
        int srow, const int* __restrict__ noffs, const int* __restrict__ csrc,
        float* __restrict__ out) {
    int node = __builtin_amdgcn_readfirstlane(blockIdx.x * 4 + (threadIdx.x >> 6));
    int lane = threadIdx.x & 63;
    const unsigned int* xp = (const unsigned int*)xin;
    const float2* x2 = (const float2*)xin;
    float alo, ahi;
    if (PACKED) {
        unsigned int u = xp[(size_t)node * srow + lane];
        alo = bf2f(u & 0xFFFFu); ahi = bf2f(u >> 16);
    } else {
        float2 v = x2[(size_t)node * 64 + lane];
        alo = v.x; ahi = v.y;
    }
    int s = noffs[node], e = noffs[node + 1];
    int i = s;
    for (; i + 8 <= e; i += 8) {
        int i0 = csrc[i + 0], i1 = csrc[i + 1], i2 = csrc[i + 2], i3 = csrc[i + 3];
        int i4 = csrc[i + 4], i5 = csrc[i + 5], i6 = csrc[i + 6], i7 = csrc[i + 7];
        if (PACKED) {
            unsigned int u0 = xp[(size_t)i0 * srow + lane];
            unsigned int u1 = xp[(size_t)i1 * srow + lane];
            unsigned int u2 = xp[(size_t)i2 * srow + lane];
            unsigned int u3 = xp[(size_t)i3 * srow + lane];
            unsigned int u4 = xp[(size_t)i4 * srow + lane];
            unsigned int u5 = xp[(size_t)i5 * srow + lane];
            unsigned int u6 = xp[(size_t)i6 * srow + lane];
            unsigned int u7 = xp[(size_t)i7 * srow + lane];
            alo += bf2f(u0 & 0xFFFFu); ahi += bf2f(u0 >> 16);
            alo += bf2f(u1 & 0xFFFFu); ahi += bf2f(u1 >> 16);
            alo += bf2f(u2 & 0xFFFFu); ahi += bf2f(u2 >> 16);
            alo += bf2f(u3 & 0xFFFFu); ahi += bf2f(u3 >> 16);
            alo += bf2f(u4 & 0xFFFFu); ahi += bf2f(u4 >> 16);
            alo += bf2f(u5 & 0xFFFFu); ahi += bf2f(u5 >> 16);
            alo += bf2f(u6 & 0xFFFFu); ahi += bf2f(u6 >> 16);
            alo += bf2f(u7 & 0xFFFFu); ahi += bf2f(u7 >> 16);
        } else {
            float2 v0 = x2[(size_t)i0 * 64 + lane];
            float2 v1 = x2[(size_t)i1 * 64 + lane];
            float2 v2 = x2[(size_t)i2 * 64 + lane];
            float2 v3 = x2[(size_t)i3 * 64 + lane];
            float2 v4 = x2[(size_t)i4 * 64 + lane];
            float2 v5 = x2[(size_t)i5 * 64 + lane];
            float2 v6 = x2[(size_t)i6 * 64 + lane];
            float2 v7 = x2[(size_t)i7 * 64 + lane];
            alo += v0.x; ahi += v0.y; alo += v1.x; ahi += v1.y;
            alo += v2.x; ahi += v2.y; alo += v3.x; ahi += v3.y;
            alo += v4.x; ahi += v4.y; alo += v5.x; ahi += v5.y;
            alo += v6.x; ahi += v6.y; alo += v7.x; ahi += v7.y;
        }
    }
    for (; i < e; ++i) {
        int sv = csrc[i];
        if (PACKED) {
            unsigned int u = xp[(size_t)sv * srow + lane];
            alo += bf2f(u & 0xFFFFu); ahi += bf2f(u >> 16);
        } else {
            float2 v = x2[(size_t)sv * 64 + lane];
            alo += v.x; ahi += v.y;
        }
    }
    if (PACKED) {
        out[(size_t)node * 128 + lane] = alo;
        out[(size_t)node * 128 + lane + 64] = ahi;
    } else {
        ((float2*)out)[(size_t)node * 64 + lane] = make_float2(alo, ahi);
    }
}

// ---------------- f32 GEMM: C = [relu](A[M,128] @ W[128,128] + b) ----------------
template<int RELU>
__global__ __launch_bounds__(256, 2) void gemm128_kernel(const float* __restrict__ A,
        const float* __restrict__ W, const float* __restrict__ bias,
        float* __restrict__ Cout, int M) {
    __shared__ float As[64][132];
    __shared__ float Ws[128][64];
    int t = threadIdx.x;
    int bm = blockIdx.x, bn = blockIdx.y;
    int row0 = bm * 64;
    {
        const float4* A4 = (const float4*)A;
        #pragma unroll
        for (int i = 0; i < 8; ++i) {
            int idx = i * 256 + t;
            int r = idx >> 5, c4 = idx & 31;
            int gr = row0 + r;
            float4 v = (gr < M) ? A4[(size_t)gr * 32 + c4] : make_float4(0.f, 0.f, 0.f, 0.f);
            *(float4*)&As[r][c4 * 4] = v;
        }
        const float4* W4 = (const float4*)W;
        #pragma unroll
        for (int i = 0; i < 8; ++i) {
            int idx = i * 256 + t;
            int k = idx >> 4, c4 = idx & 15;
            float4 v = W4[(size_t)k * 32 + bn * 16 + c4];
            *(float4*)&Ws[k][c4 * 4] = v;
        }
    }
    __syncthreads();
    int tc = t & 15, tr = t >> 4;
    int c0 = tc * 4;
    float acc[4][4] = {};
    for (int k = 0; k < 128; k += 4) {
        float4 a[4], w[4];
        #pragma unroll
        for (int j = 0; j < 4; ++j) a[j] = *(const float4*)&As[tr * 4 + j][k];
        #pragma unroll
        for (int kk = 0; kk < 4; ++kk) w[kk] = *(const float4*)&Ws[k + kk][c0];
        #pragma unroll
        for (int j = 0; j < 4; ++j) {
            float av[4] = {a[j].x, a[j].y, a[j].z, a[j].w};
            #pragma unroll
            for (int kk = 0; kk < 4; ++kk) {
                acc[j][0] += av[kk] * w[kk].x;
                acc[j][1] += av[kk] * w[kk].y;
                acc[j][2] += av[kk] * w[kk].z;
                acc[j][3] += av[kk] * w[kk].w;
            }
        }
    }
    float4 b4 = *(const float4*)&bias[bn * 64 + c0];
    #pragma unroll
    for (int j = 0; j < 4; ++j) {
        int gr = row0 + tr * 4 + j;
        if (gr < M) {
            float4 v = make_float4(acc[j][0] + b4.x, acc[j][1] + b4.y,
                                   acc[j][2] + b4.z, acc[j][3] + b4.w);
            if (RELU) {
                v.x = fmaxf(v.x, 0.f); v.y = fmaxf(v.y, 0.f);
                v.z = fmaxf(v.z, 0.f); v.w = fmaxf(v.w, 0.f);
            }
            *(float4*)&Cout[(size_t)gr * 128 + bn * 64 + c0] = v;
        }
    }
}

// ---------------- BN stats: per-channel sum & sumsq ----------------
__global__ void bn_stats_kernel(const float* __restrict__ U, float* __restrict__ stats) {
    int tid = blockIdx.x * 256 + threadIdx.x;
    int chn = tid & 127;
    float s = 0.f, sq = 0.f;
    const int total = NN * 128;
    for (int i = tid; i < total; i += 2048 * 256) {
        float v = U[i];
        s += v; sq += v * v;
    }
    atomicAdd(&stats[chn], s);
    atomicAdd(&stats[128 + chn], sq);
}

// ---------------- BN + ReLU + in-place bf16 pack (row prefix, stride 128 u32) ----------------
__global__ void bn_relu_pack_kernel(float* __restrict__ F, const float* __restrict__ stats,
        const float* __restrict__ gamma, const float* __restrict__ beta) {
    int tid = blockIdx.x * 256 + threadIdx.x;   // NN*64 exact
    int n = tid >> 6, l = tid & 63;
    const float inv = 1.0f / NN;
    float u0 = F[(size_t)n * 128 + l];
    float u1 = F[(size_t)n * 128 + l + 64];
    float m0 = stats[l] * inv;
    float v0 = stats[128 + l] * inv - m0 * m0;
    float m1 = stats[l + 64] * inv;
    float v1 = stats[192 + l] * inv - m1 * m1;
    float o0 = fmaxf((u0 - m0) * rsqrtf(v0 + BN_EPS) * gamma[l] + beta[l], 0.f);
    float o1 = fmaxf((u1 - m1) * rsqrtf(v1 + BN_EPS) * gamma[l + 64] + beta[l + 64], 0.f);
    ((unsigned int*)F)[(size_t)n * 128 + l] =
        (unsigned int)f2bf(o0) | ((unsigned int)f2bf(o1) << 16);
}

// ---------------- pooling over packed rows ----------------
__global__ void pool_kernel(const unsigned int* __restrict__ hb, int srow,
                            const int* __restrict__ batch, float* __restrict__ pooled) {
    int g = blockIdx.x;
    int l = threadIdx.x;   // 64
    int a = 0, b = NN;
    while (a < b) { int m = (a + b) >> 1; if (batch[m] < g) a = m + 1; else b = m; }
    int start = a;
    b = NN;
    while (a < b) { int m = (a + b) >> 1; if (batch[m] < g + 1) a = m + 1; else b = m; }
    int end = a;
    float s0 = 0.f, s1 = 0.f;
    for (int i = start; i < end; ++i) {
        unsigned int u = hb[(size_t)i * srow + l];
        s0 += bf2f(u & 0xFFFFu);
        s1 += bf2f(u >> 16);
    }
    pooled[g * 128 + l] = s0;
    pooled[g * 128 + l + 64] = s1;
}

// ---------------- head: logits + log_softmax ----------------
__global__ void head_kernel(const float* __restrict__ pooled, const float* __restrict__ Wlin,
                            const float* __restrict__ blin, float* __restrict__ out) {
    int g = blockIdx.x;
    int lane = threadIdx.x;  // 64
    float2 p = ((const float2*)pooled)[g * 64 + lane];
    float l[10];
    #pragma unroll
    for (int o = 0; o < 10; ++o) {
        float partial = p.x * Wlin[(2 * lane) * 10 + o] + p.y * Wlin[(2 * lane + 1) * 10 + o];
        #pragma unroll
        for (int m = 1; m < 64; m <<= 1) partial += __shfl_xor(partial, m, 64);
        l[o] = partial + blin[o];
    }
    float mx = l[0];
    #pragma unroll
    for (int o = 1; o < 10; ++o) mx = fmaxf(mx, l[o]);
    float se = 0.f;
    #pragma unroll
    for (int o = 0; o < 10; ++o) se += expf(l[o] - mx);
    float lse = mx + logf(se);
    if (lane == 0) {
        #pragma unroll
        for (int o = 0; o < 10; ++o) out[g * 10 + o] = l[o] - lse;
    }
}

extern "C" void kernel_launch(void* const* d_in, const int* in_sizes, int n_in,
                              void* d_out, int out_size, void* d_ws, size_t ws_size,
                              hipStream_t stream) {
    const float* x    = (const float*)d_in[0];
    const int*   edge = (const int*)d_in[1];   // [2][NE]
    const int*   batch= (const int*)d_in[2];
    const float* W1a  = (const float*)d_in[3];
    const float* b1a  = (const float*)d_in[4];
    const float* W1b  = (const float*)d_in[5];
    const float* b1b  = (const float*)d_in[6];
    const float* g1   = (const float*)d_in[7];
    const float* be1  = (const float*)d_in[8];
    const float* W2a  = (const float*)d_in[9];
    const float* b2a  = (const float*)d_in[10];
    const float* W2b  = (const float*)d_in[11];
    const float* b2b  = (const float*)d_in[12];
    const float* g2   = (const float*)d_in[13];
    const float* be2  = (const float*)d_in[14];
    const float* Wlin = (const float*)d_in[15];
    const float* blin = (const float*)d_in[16];
    float* out = (float*)d_out;

    char* ws = (char*)d_ws;
    size_t off = 0;
    auto alloc = [&](size_t bytes) -> void* {
        void* p = ws + off; off += (bytes + 255) & ~(size_t)255; return p;
    };
    float* F1     = (float*)alloc((size_t)NN * 128 * 4);
    float* F2     = (float*)alloc((size_t)NN * 128 * 4);
    unsigned int* ebin = (unsigned int*)alloc((size_t)NE * 4);
    int*   csrc   = (int*)alloc((size_t)NE * 4);
    int*   noffs  = (int*)alloc((NN + 1) * 4);
    int*   bcnt   = (int*)alloc(NBKT * 4);
    int*   bbase  = (int*)alloc(NBKT * 4);
    int*   bcur   = (int*)alloc(NBKT * 4);
    float* stats1 = (float*)alloc(256 * 4);
    float* stats2 = (float*)alloc(256 * 4);
    float* pooled = (float*)alloc(NG * 128 * 4);
    size_t base_need = off;
    bool havePx = (ws_size >= base_need + (size_t)NN * 64 * 4 + 256);
    unsigned int* Px = havePx ? (unsigned int*)alloc((size_t)NN * 64 * 4) : nullptr;

    const int* srcI = edge;
    const int* dstI = edge + NE;

    hipMemsetAsync(bcnt, 0, NBKT * 4, stream);
    hipMemsetAsync(stats1, 0, 256 * 4, stream);
    hipMemsetAsync(stats2, 0, 256 * 4, stream);

    bucket_count_kernel<<<NBINBLK, 256, 0, stream>>>(dstI, bcnt);
    bucket_scan_kernel<<<1, 1024, 0, stream>>>(bcnt, bbase, bcur);
    bin_kernel<<<NBINBLK, 256, 0, stream>>>(srcI, dstI, bcur, ebin);
    sort_kernel<<<NBKT, 256, 0, stream>>>(ebin, bbase, bcnt, noffs, csrc);

    dim3 ggrid(1563, 2);
    // ---- layer 1 ----
    if (havePx) {
        pack_x_kernel<<<25000, 256, 0, stream>>>(x, Px);
        aggregate_gather_kernel<1><<<25000, 256, 0, stream>>>(Px, 64, noffs, csrc, F1);
    } else {
        aggregate_gather_kernel<0><<<25000, 256, 0, stream>>>(x, 128, noffs, csrc, F1);
    }
    gemm128_kernel<1><<<ggrid, 256, 0, stream>>>(F1, W1a, b1a, F2, NN);
    gemm128_kernel<0><<<ggrid, 256, 0, stream>>>(F2, W1b, b1b, F1, NN);
    bn_stats_kernel<<<2048, 256, 0, stream>>>(F1, stats1);
    bn_relu_pack_kernel<<<25000, 256, 0, stream>>>(F1, stats1, g1, be1);
    // ---- layer 2 ----
    aggregate_gather_kernel<1><<<25000, 256, 0, stream>>>(F1, 128, noffs, csrc, F2);
    gemm128_kernel<1><<<ggrid, 256, 0, stream>>>(F2, W2a, b2a, F1, NN);
    gemm128_kernel<0><<<ggrid, 256, 0, stream>>>(F1, W2b, b2b, F2, NN);
    bn_stats_kernel<<<2048, 256, 0, stream>>>(F2, stats2);
    bn_relu_pack_kernel<<<25000, 256, 0, stream>>>(F2, stats2, g2, be2);

    pool_kernel<<<NG, 64, 0, stream>>>((const unsigned int*)F2, 128, batch, pooled);
    head_kernel<<<NG, 64, 0, stream>>>(pooled, Wlin, blin, out);
}